// Round 7
// baseline (157.800 us; speedup 1.0000x reference)
//
#include <hip/hip_runtime.h>
#include <hip/hip_bf16.h>

typedef __attribute__((ext_vector_type(8))) short bf16x8;
typedef __attribute__((ext_vector_type(4))) float f32x4;

#define DEV static __device__ __forceinline__

DEV unsigned short f2bf(float f) {
    union { __hip_bfloat16 h; unsigned short u; } cv;
    cv.h = __float2bfloat16(f);
    return cv.u;
}

typedef __attribute__((address_space(1))) const void gas_t;
typedef __attribute__((address_space(3))) void las_t;

DEV void gl_lds16(const unsigned short* g, unsigned short* l) {
    __builtin_amdgcn_global_load_lds((gas_t*)g, (las_t*)l, 16, 0, 0);
}

// ---------------------------------------------------------------------------
// Kernel 1 (v9): fused preamble. Blocks 0..191: W fp32 -> WT bf16 transposed
// (W0 pre-scaled by 1/sqrt(512)). Blocks 192..4287: x fp32 -> xb bf16 copy.
// One launch instead of two (removes a serialization gap).
// ---------------------------------------------------------------------------
__global__ __launch_bounds__(256, 2) void pre_kernel(const float* __restrict__ W,
                                                     unsigned short* __restrict__ WT,
                                                     const float* __restrict__ x,
                                                     unsigned short* __restrict__ xb) {
    __shared__ __align__(16) unsigned short T[64][72];
    int bid = blockIdx.x;
    if (bid >= 192) {
        size_t i = ((size_t)(bid - 192) * 256 + threadIdx.x) * 8;
        float4 f0 = *(const float4*)(x + i);
        float4 f1 = *(const float4*)(x + i + 4);
        bf16x8 u;
        u[0] = (short)f2bf(f0.x); u[1] = (short)f2bf(f0.y);
        u[2] = (short)f2bf(f0.z); u[3] = (short)f2bf(f0.w);
        u[4] = (short)f2bf(f1.x); u[5] = (short)f2bf(f1.y);
        u[6] = (short)f2bf(f1.z); u[7] = (short)f2bf(f1.w);
        *(bf16x8*)(xb + i) = u;
        return;
    }
    int w = bid >> 6;
    int rem = bid & 63;
    int kt = rem >> 3, nt = rem & 7;
    int t = threadIdx.x;
    int r = t >> 2, cq = t & 3;
    const float* src = W + ((size_t)(w * 512 + kt * 64 + r)) * 512 + nt * 64 + cq * 16;
    float sc = (w == 0) ? 0.04419417382415922f : 1.0f;  // 1/sqrt(512)
    #pragma unroll
    for (int i = 0; i < 4; i++) {
        float4 f = *(const float4*)(src + 4 * i);
        T[r][cq * 16 + 4 * i + 0] = f2bf(f.x * sc);
        T[r][cq * 16 + 4 * i + 1] = f2bf(f.y * sc);
        T[r][cq * 16 + 4 * i + 2] = f2bf(f.z * sc);
        T[r][cq * 16 + 4 * i + 3] = f2bf(f.w * sc);
    }
    __syncthreads();
    int n = t >> 2, kq = t & 3;
    bf16x8 v0, v1;
    #pragma unroll
    for (int e = 0; e < 8; e++) v0[e] = (short)T[kq * 16 + e][n];
    #pragma unroll
    for (int e = 0; e < 8; e++) v1[e] = (short)T[kq * 16 + 8 + e][n];
    unsigned short* dst = WT + ((size_t)(w * 512 + nt * 64 + n)) * 512 + kt * 64 + kq * 16;
    *(bf16x8*)dst = v0;
    *(bf16x8*)(dst + 8) = v1;
}

// ---------------------------------------------------------------------------
// Kernel 2 (unchanged from v8): QKV projection, global_load_lds staging of
// both operands, double-buffered, 1 barrier/k-chunk.
// ---------------------------------------------------------------------------
#define STAGE_P(kk) do {                                                          \
    _Pragma("unroll")                                                             \
    for (int i_ = 0; i_ < 2; i_++) {                                              \
        int r_ = wid * 32 + i_ * 16 + (lane >> 2);                                \
        int ch_ = (lane & 3) ^ (r_ & 3);                                          \
        gl_lds16(xp + (size_t)r_ * 512 + (kk) * 32 + ch_ * 8,                     \
                 &As[(kk) & 1][(wid * 32 + i_ * 16) * 32]);                       \
        gl_lds16(wp + (size_t)r_ * 512 + (kk) * 32 + ch_ * 8,                     \
                 &Bs[(kk) & 1][(wid * 32 + i_ * 16) * 32]);                       \
    }                                                                             \
} while (0)

__global__ __launch_bounds__(256, 2) void proj_kernel(const unsigned short* __restrict__ xb,
        const unsigned short* __restrict__ WT,
        unsigned short* __restrict__ Qo, unsigned short* __restrict__ Ko,
        unsigned short* __restrict__ VTo) {
    __shared__ __align__(16) unsigned short As[2][128 * 32];  // 16 KB
    __shared__ __align__(16) unsigned short Bs[2][128 * 32];  // 16 KB
    __shared__ __align__(16) unsigned short Cs[128][132];     // 33.8 KB

    int bid = blockIdx.x;
    int swz = (bid & 7) * 192 + (bid >> 3);
    int mt = swz / 12;
    int rem = swz - mt * 12;
    int w = rem >> 2, nt = rem & 3;
    int tid = threadIdx.x;
    int lane = tid & 63, wid = tid >> 6;
    int wm = wid >> 1, wn = wid & 1;
    int c = lane & 15, g = lane >> 4;

    const unsigned short* xp = xb + (size_t)(mt * 128) * 512;
    const unsigned short* wp = WT + ((size_t)(w * 512 + nt * 128)) * 512;

    const f32x4 fz = {0.f, 0.f, 0.f, 0.f};
    f32x4 acc[4][4];
    #pragma unroll
    for (int i = 0; i < 4; i++)
        #pragma unroll
        for (int j = 0; j < 4; j++) acc[i][j] = fz;

    STAGE_P(0);
    for (int kk = 0; kk < 16; kk++) {
        __syncthreads();                 // buf[kk&1] DMA drained (vmcnt0)
        if (kk + 1 < 16) STAGE_P(kk + 1);
        const unsigned short* Ac = &As[kk & 1][0];
        const unsigned short* Bc = &Bs[kk & 1][0];
        bf16x8 a[4], bb[4];
        #pragma unroll
        for (int rt = 0; rt < 4; rt++) {
            int row = wm * 64 + rt * 16 + c;
            a[rt] = *(const bf16x8*)&Ac[row * 32 + ((g ^ (row & 3)) * 8)];
        }
        #pragma unroll
        for (int ct = 0; ct < 4; ct++) {
            int row = wn * 64 + ct * 16 + c;
            bb[ct] = *(const bf16x8*)&Bc[row * 32 + ((g ^ (row & 3)) * 8)];
        }
        __builtin_amdgcn_s_setprio(1);
        #pragma unroll
        for (int rt = 0; rt < 4; rt++)
            #pragma unroll
            for (int ct = 0; ct < 4; ct++)
                acc[rt][ct] = __builtin_amdgcn_mfma_f32_16x16x32_bf16(a[rt], bb[ct], acc[rt][ct], 0, 0, 0);
        __builtin_amdgcn_s_setprio(0);
    }

    if (w < 2) {
        unsigned short* dst = (w == 0) ? Qo : Ko;
        #pragma unroll
        for (int rt = 0; rt < 4; rt++)
            #pragma unroll
            for (int ct = 0; ct < 4; ct++)
                #pragma unroll
                for (int r = 0; r < 4; r++) {
                    int grow = mt * 128 + wm * 64 + rt * 16 + g * 4 + r;
                    int gcol = nt * 128 + wn * 64 + ct * 16 + c;
                    dst[(size_t)grow * 512 + gcol] = f2bf(acc[rt][ct][r]);
                }
    } else {
        #pragma unroll
        for (int rt = 0; rt < 4; rt++)
            #pragma unroll
            for (int ct = 0; ct < 4; ct++)
                #pragma unroll
                for (int r = 0; r < 4; r++)
                    Cs[wm * 64 + rt * 16 + g * 4 + r][wn * 64 + ct * 16 + c] = f2bf(acc[rt][ct][r]);
        __syncthreads();
        int dcol = tid >> 1, sh = tid & 1;
        int bb2 = mt >> 4;
        int s0r = (mt & 15) * 128;
        #pragma unroll
        for (int jj = 0; jj < 8; jj++) {
            bf16x8 v;
            #pragma unroll
            for (int e = 0; e < 8; e++) v[e] = (short)Cs[sh * 64 + jj * 8 + e][dcol];
            *(bf16x8*)(VTo + ((size_t)(bb2 * 512 + nt * 128 + dcol)) * 2048 + s0r + sh * 64 + jj * 8) = v;
        }
    }
}

// ---------------------------------------------------------------------------
// Kernel 3 (v9): v8 wave-specialized attention +
//  (a) score QK^T split into 4 independent accumulator chains (2x MFMA ILP
//      on the serial critical path),
//  (b) s_setprio(1) around MFMA clusters (T5: score vs PV role diversity on
//      each SIMD gives the scheduler something to arbitrate).
// ---------------------------------------------------------------------------
#define STAGE_K(tt) do {                                                        \
    _Pragma("unroll")                                                           \
    for (int i_ = 0; i_ < 4; i_++) {                                            \
        int r_ = wid * 4 + i_;                                                  \
        gl_lds16(Kb + (size_t)((tt) * 64 + r_) * 512 + ((lane ^ (r_ & 7)) * 8), \
                 &Ks[(tt) & 1][r_ * 512]);                                      \
    }                                                                           \
} while (0)

__global__ __launch_bounds__(1024, 4) void attn_kernel(const unsigned short* __restrict__ Qg,
        const unsigned short* __restrict__ Kg, const unsigned short* __restrict__ VTg,
        float* __restrict__ out) {
    __shared__ __align__(16) unsigned short Ks[2][64 * 512];  // 128 KB, swizzled
    __shared__ __align__(16) unsigned short Ps[2][64][72];    // 18.4 KB, dbuf
    __shared__ float psum_s[64][2];

    int bid = blockIdx.x;
    int swz = (bid & 7) * 32 + (bid >> 3);  // XCD x owns batch x
    int b = swz >> 5, qt = swz & 31;
    int tid = threadIdx.x;
    int lane = tid & 63, wid = tid >> 6;    // wid 0..15
    int c = lane & 15, g = lane >> 4;

    const unsigned short* Qb = Qg + ((size_t)(b * 2048 + qt * 64)) * 512;
    const unsigned short* Kb = Kg + ((size_t)b * 2048) * 512;
    const unsigned short* Vb = VTg + ((size_t)b * 512) * 2048;

    // ---- stage Q (swizzled source) into Ks[0] — all waves
    #pragma unroll
    for (int i = 0; i < 4; i++) {
        int r = wid * 4 + i;
        gl_lds16(Qb + (size_t)r * 512 + ((lane ^ (r & 7)) * 8), &Ks[0][r * 512]);
    }

    if (wid < 8) {
        // ================= score waves =================
        int sqg = wid >> 1;          // q-row group (0..3), two waves each
        int skg = (wid & 1) * 2;     // first of two 16-col kv groups (0 or 2)
        __syncthreads();             // A: Q DMA done (vmcnt0)
        bf16x8 qf[16];
        {
            int row = sqg * 16 + c;
            #pragma unroll
            for (int ks = 0; ks < 16; ks++)
                qf[ks] = *(const bf16x8*)&Ks[0][row * 512 + (((ks * 4 + g) ^ (row & 7)) * 8)];
        }
        __syncthreads();             // B: Q reads done before K(0) overwrite
        STAGE_K(0);

        float accs[8];
        #pragma unroll
        for (int j = 0; j < 8; j++) accs[j] = 0.0f;

        for (int t = 0; t < 32; t++) {
            __syncthreads();         // K(t) staged; Ps(t) buffer free
            if (t + 1 < 32) STAGE_K(t + 1);

            const unsigned short* KsC = &Ks[t & 1][0];
            const f32x4 fz = {0.f, 0.f, 0.f, 0.f};
            f32x4 s0a = fz, s0b = fz, s1a = fz, s1b = fz;
            int kr0 = skg * 16 + c;
            int kr1 = kr0 + 16;
            __builtin_amdgcn_s_setprio(1);
            #pragma unroll
            for (int ks = 0; ks < 16; ks += 2) {
                bf16x8 bk0 = *(const bf16x8*)&KsC[kr0 * 512 + (((ks * 4 + g) ^ (kr0 & 7)) * 8)];
                bf16x8 bk1 = *(const bf16x8*)&KsC[kr1 * 512 + (((ks * 4 + g) ^ (kr1 & 7)) * 8)];
                bf16x8 bk0n = *(const bf16x8*)&KsC[kr0 * 512 + ((((ks + 1) * 4 + g) ^ (kr0 & 7)) * 8)];
                bf16x8 bk1n = *(const bf16x8*)&KsC[kr1 * 512 + ((((ks + 1) * 4 + g) ^ (kr1 & 7)) * 8)];
                s0a = __builtin_amdgcn_mfma_f32_16x16x32_bf16(qf[ks], bk0, s0a, 0, 0, 0);
                s1a = __builtin_amdgcn_mfma_f32_16x16x32_bf16(qf[ks], bk1, s1a, 0, 0, 0);
                s0b = __builtin_amdgcn_mfma_f32_16x16x32_bf16(qf[ks + 1], bk0n, s0b, 0, 0, 0);
                s1b = __builtin_amdgcn_mfma_f32_16x16x32_bf16(qf[ks + 1], bk1n, s1b, 0, 0, 0);
            }
            __builtin_amdgcn_s_setprio(0);
            f32x4 s0 = s0a + s0b;
            f32x4 s1 = s1a + s1b;
            unsigned short* PsW = &Ps[t & 1][0][0];
            #pragma unroll
            for (int r = 0; r < 4; r++) {
                int row = sqg * 16 + g * 4 + r;
                float p0 = __expf(s0[r]);
                float p1 = __expf(s1[r]);
                accs[r] += p0;
                accs[4 + r] += p1;
                PsW[row * 72 + skg * 16 + c] = f2bf(p0);
                PsW[row * 72 + (skg + 1) * 16 + c] = f2bf(p1);
            }
        }

        // final row-sum reduction into psum_s
        #pragma unroll
        for (int r = 0; r < 4; r++) {
            float v = accs[r] + accs[4 + r];
            v += __shfl_xor(v, 1);
            v += __shfl_xor(v, 2);
            v += __shfl_xor(v, 4);
            v += __shfl_xor(v, 8);
            if (c == 0) psum_s[sqg * 16 + g * 4 + r][wid & 1] = v;
        }
        __syncthreads();             // C: Ps(31) + psum_s published
    } else {
        // ================= PV waves =================
        int pcol = (wid - 8) * 64;   // d-column base (0..448)
        const unsigned short* Vp = Vb + (size_t)(pcol + c) * 2048 + g * 8;
        __syncthreads();             // A
        __syncthreads();             // B
        STAGE_K(0);

        f32x4 o[16];
        {
            const f32x4 fz = {0.f, 0.f, 0.f, 0.f};
            #pragma unroll
            for (int i = 0; i < 16; i++) o[i] = fz;
        }
        bf16x8 bva[4];               // V(t, h0) prefetched one tile ahead
        #pragma unroll
        for (int ct = 0; ct < 4; ct++)
            bva[ct] = *(const bf16x8*)(Vp + (size_t)(ct * 16) * 2048);

        for (int t = 0; t < 32; t++) {
            __syncthreads();         // K(t) staged; Ps(t-1) visible
            if (t + 1 < 32) STAGE_K(t + 1);
            if (t > 0) {
                int tp = t - 1;
                const unsigned short* PsR = &Ps[tp & 1][0][0];
                bf16x8 bvb[4];       // V(tp, h1): issue now, use after h0 MFMAs
                #pragma unroll
                for (int ct = 0; ct < 4; ct++)
                    bvb[ct] = *(const bf16x8*)(Vp + (size_t)(ct * 16) * 2048 + tp * 64 + 32);
                __builtin_amdgcn_s_setprio(1);
                #pragma unroll
                for (int rt = 0; rt < 4; rt++) {
                    bf16x8 pa = *(const bf16x8*)&PsR[(rt * 16 + c) * 72 + g * 8];
                    #pragma unroll
                    for (int ct = 0; ct < 4; ct++)
                        o[rt * 4 + ct] = __builtin_amdgcn_mfma_f32_16x16x32_bf16(
                            pa, bva[ct], o[rt * 4 + ct], 0, 0, 0);
                }
                __builtin_amdgcn_s_setprio(0);
                #pragma unroll
                for (int ct = 0; ct < 4; ct++)   // prefetch V(t, h0) for next tile
                    bva[ct] = *(const bf16x8*)(Vp + (size_t)(ct * 16) * 2048 + t * 64);
                __builtin_amdgcn_s_setprio(1);
                #pragma unroll
                for (int rt = 0; rt < 4; rt++) {
                    bf16x8 pa = *(const bf16x8*)&PsR[(rt * 16 + c) * 72 + 32 + g * 8];
                    #pragma unroll
                    for (int ct = 0; ct < 4; ct++)
                        o[rt * 4 + ct] = __builtin_amdgcn_mfma_f32_16x16x32_bf16(
                            pa, bvb[ct], o[rt * 4 + ct], 0, 0, 0);
                }
                __builtin_amdgcn_s_setprio(0);
            }
        }
        __syncthreads();             // C: Ps(31) + psum_s visible
        {
            const unsigned short* PsR = &Ps[31 & 1][0][0];
            bf16x8 bvb[4];
            #pragma unroll
            for (int ct = 0; ct < 4; ct++)
                bvb[ct] = *(const bf16x8*)(Vp + (size_t)(ct * 16) * 2048 + 31 * 64 + 32);
            #pragma unroll
            for (int rt = 0; rt < 4; rt++) {
                bf16x8 pa = *(const bf16x8*)&PsR[(rt * 16 + c) * 72 + g * 8];
                #pragma unroll
                for (int ct = 0; ct < 4; ct++)
                    o[rt * 4 + ct] = __builtin_amdgcn_mfma_f32_16x16x32_bf16(
                        pa, bva[ct], o[rt * 4 + ct], 0, 0, 0);
            }
            #pragma unroll
            for (int rt = 0; rt < 4; rt++) {
                bf16x8 pa = *(const bf16x8*)&PsR[(rt * 16 + c) * 72 + 32 + g * 8];
                #pragma unroll
                for (int ct = 0; ct < 4; ct++)
                    o[rt * 4 + ct] = __builtin_amdgcn_mfma_f32_16x16x32_bf16(
                        pa, bvb[ct], o[rt * 4 + ct], 0, 0, 0);
            }
        }

        float* ob = out + ((size_t)(b * 2048 + qt * 64)) * 512;
        #pragma unroll
        for (int rt = 0; rt < 4; rt++)
            #pragma unroll
            for (int r = 0; r < 4; r++) {
                int lrow = rt * 16 + g * 4 + r;
                float l = psum_s[lrow][0] + psum_s[lrow][1];
                float inv = 1.0f / l;
                #pragma unroll
                for (int ct = 0; ct < 4; ct++)
                    ob[(size_t)lrow * 512 + pcol + ct * 16 + c] = o[rt * 4 + ct][r] * inv;
            }
    }
}

// ---------------------------------------------------------------------------
extern "C" void kernel_launch(void* const* d_in, const int* in_sizes, int n_in,
                              void* d_out, int out_size, void* d_ws, size_t ws_size,
                              hipStream_t stream) {
    const float* x = (const float*)d_in[0];   // [8][2048][512] fp32
    const float* W = (const float*)d_in[1];   // [3][512][512] fp32
    float* out = (float*)d_out;               // [8][2048][512] fp32
    char* ws = (char*)d_ws;
    unsigned short* WT = (unsigned short*)(ws);
    unsigned short* Q  = (unsigned short*)(ws + (size_t)2  * 1024 * 1024);
    unsigned short* K  = (unsigned short*)(ws + (size_t)18 * 1024 * 1024);
    unsigned short* VT = (unsigned short*)(ws + (size_t)34 * 1024 * 1024);
    // x-bf16 scratch lives in the OUTPUT buffer (16.7 MB of 33.5 MB); it is
    // fully dead before attn_kernel overwrites every element of out.
    unsigned short* xb = (unsigned short*)d_out;

    pre_kernel<<<4288, 256, 0, stream>>>(W, WT, x, xb);
    proj_kernel<<<1536, 256, 0, stream>>>(xb, WT, Q, K, VT);
    attn_kernel<<<256, 1024, 0, stream>>>(Q, K, VT, out);
}

// Round 8
// 149.135 us; speedup vs baseline: 1.0581x; 1.0581x over previous
//
#include <hip/hip_runtime.h>
#include <hip/hip_bf16.h>

typedef __attribute__((ext_vector_type(8))) short bf16x8;
typedef __attribute__((ext_vector_type(4))) float f32x4;

#define DEV static __device__ __forceinline__

DEV unsigned short f2bf(float f) {
    union { __hip_bfloat16 h; unsigned short u; } cv;
    cv.h = __float2bfloat16(f);
    return cv.u;
}

typedef __attribute__((address_space(1))) const void gas_t;
typedef __attribute__((address_space(3))) void las_t;

DEV void gl_lds16(const unsigned short* g, unsigned short* l) {
    __builtin_amdgcn_global_load_lds((gas_t*)g, (las_t*)l, 16, 0, 0);
}

// ---------------------------------------------------------------------------
// Kernel 1 (v9, kept): fused preamble. Blocks 0..191: W fp32 -> WT bf16
// transposed (W0 pre-scaled by 1/sqrt(512)). Blocks 192..4287: x -> xb bf16.
// ---------------------------------------------------------------------------
__global__ __launch_bounds__(256, 2) void pre_kernel(const float* __restrict__ W,
                                                     unsigned short* __restrict__ WT,
                                                     const float* __restrict__ x,
                                                     unsigned short* __restrict__ xb) {
    __shared__ __align__(16) unsigned short T[64][72];
    int bid = blockIdx.x;
    if (bid >= 192) {
        size_t i = ((size_t)(bid - 192) * 256 + threadIdx.x) * 8;
        float4 f0 = *(const float4*)(x + i);
        float4 f1 = *(const float4*)(x + i + 4);
        bf16x8 u;
        u[0] = (short)f2bf(f0.x); u[1] = (short)f2bf(f0.y);
        u[2] = (short)f2bf(f0.z); u[3] = (short)f2bf(f0.w);
        u[4] = (short)f2bf(f1.x); u[5] = (short)f2bf(f1.y);
        u[6] = (short)f2bf(f1.z); u[7] = (short)f2bf(f1.w);
        *(bf16x8*)(xb + i) = u;
        return;
    }
    int w = bid >> 6;
    int rem = bid & 63;
    int kt = rem >> 3, nt = rem & 7;
    int t = threadIdx.x;
    int r = t >> 2, cq = t & 3;
    const float* src = W + ((size_t)(w * 512 + kt * 64 + r)) * 512 + nt * 64 + cq * 16;
    float sc = (w == 0) ? 0.04419417382415922f : 1.0f;  // 1/sqrt(512)
    #pragma unroll
    for (int i = 0; i < 4; i++) {
        float4 f = *(const float4*)(src + 4 * i);
        T[r][cq * 16 + 4 * i + 0] = f2bf(f.x * sc);
        T[r][cq * 16 + 4 * i + 1] = f2bf(f.y * sc);
        T[r][cq * 16 + 4 * i + 2] = f2bf(f.z * sc);
        T[r][cq * 16 + 4 * i + 3] = f2bf(f.w * sc);
    }
    __syncthreads();
    int n = t >> 2, kq = t & 3;
    bf16x8 v0, v1;
    #pragma unroll
    for (int e = 0; e < 8; e++) v0[e] = (short)T[kq * 16 + e][n];
    #pragma unroll
    for (int e = 0; e < 8; e++) v1[e] = (short)T[kq * 16 + 8 + e][n];
    unsigned short* dst = WT + ((size_t)(w * 512 + nt * 64 + n)) * 512 + kt * 64 + kq * 16;
    *(bf16x8*)dst = v0;
    *(bf16x8*)(dst + 8) = v1;
}

// ---------------------------------------------------------------------------
// Kernel 2 (v9, kept): QKV projection, global_load_lds staging of both
// operands, double-buffered, 1 barrier/k-chunk, setprio around MFMA cluster.
// ---------------------------------------------------------------------------
#define STAGE_P(kk) do {                                                          \
    _Pragma("unroll")                                                             \
    for (int i_ = 0; i_ < 2; i_++) {                                              \
        int r_ = wid * 32 + i_ * 16 + (lane >> 2);                                \
        int ch_ = (lane & 3) ^ (r_ & 3);                                          \
        gl_lds16(xp + (size_t)r_ * 512 + (kk) * 32 + ch_ * 8,                     \
                 &As[(kk) & 1][(wid * 32 + i_ * 16) * 32]);                       \
        gl_lds16(wp + (size_t)r_ * 512 + (kk) * 32 + ch_ * 8,                     \
                 &Bs[(kk) & 1][(wid * 32 + i_ * 16) * 32]);                       \
    }                                                                             \
} while (0)

__global__ __launch_bounds__(256, 2) void proj_kernel(const unsigned short* __restrict__ xb,
        const unsigned short* __restrict__ WT,
        unsigned short* __restrict__ Qo, unsigned short* __restrict__ Ko,
        unsigned short* __restrict__ VTo) {
    __shared__ __align__(16) unsigned short As[2][128 * 32];  // 16 KB
    __shared__ __align__(16) unsigned short Bs[2][128 * 32];  // 16 KB
    __shared__ __align__(16) unsigned short Cs[128][132];     // 33.8 KB

    int bid = blockIdx.x;
    int swz = (bid & 7) * 192 + (bid >> 3);
    int mt = swz / 12;
    int rem = swz - mt * 12;
    int w = rem >> 2, nt = rem & 3;
    int tid = threadIdx.x;
    int lane = tid & 63, wid = tid >> 6;
    int wm = wid >> 1, wn = wid & 1;
    int c = lane & 15, g = lane >> 4;

    const unsigned short* xp = xb + (size_t)(mt * 128) * 512;
    const unsigned short* wp = WT + ((size_t)(w * 512 + nt * 128)) * 512;

    const f32x4 fz = {0.f, 0.f, 0.f, 0.f};
    f32x4 acc[4][4];
    #pragma unroll
    for (int i = 0; i < 4; i++)
        #pragma unroll
        for (int j = 0; j < 4; j++) acc[i][j] = fz;

    STAGE_P(0);
    for (int kk = 0; kk < 16; kk++) {
        __syncthreads();                 // buf[kk&1] DMA drained (vmcnt0)
        if (kk + 1 < 16) STAGE_P(kk + 1);
        const unsigned short* Ac = &As[kk & 1][0];
        const unsigned short* Bc = &Bs[kk & 1][0];
        bf16x8 a[4], bb[4];
        #pragma unroll
        for (int rt = 0; rt < 4; rt++) {
            int row = wm * 64 + rt * 16 + c;
            a[rt] = *(const bf16x8*)&Ac[row * 32 + ((g ^ (row & 3)) * 8)];
        }
        #pragma unroll
        for (int ct = 0; ct < 4; ct++) {
            int row = wn * 64 + ct * 16 + c;
            bb[ct] = *(const bf16x8*)&Bc[row * 32 + ((g ^ (row & 3)) * 8)];
        }
        __builtin_amdgcn_s_setprio(1);
        #pragma unroll
        for (int rt = 0; rt < 4; rt++)
            #pragma unroll
            for (int ct = 0; ct < 4; ct++)
                acc[rt][ct] = __builtin_amdgcn_mfma_f32_16x16x32_bf16(a[rt], bb[ct], acc[rt][ct], 0, 0, 0);
        __builtin_amdgcn_s_setprio(0);
    }

    if (w < 2) {
        unsigned short* dst = (w == 0) ? Qo : Ko;
        #pragma unroll
        for (int rt = 0; rt < 4; rt++)
            #pragma unroll
            for (int ct = 0; ct < 4; ct++)
                #pragma unroll
                for (int r = 0; r < 4; r++) {
                    int grow = mt * 128 + wm * 64 + rt * 16 + g * 4 + r;
                    int gcol = nt * 128 + wn * 64 + ct * 16 + c;
                    dst[(size_t)grow * 512 + gcol] = f2bf(acc[rt][ct][r]);
                }
    } else {
        #pragma unroll
        for (int rt = 0; rt < 4; rt++)
            #pragma unroll
            for (int ct = 0; ct < 4; ct++)
                #pragma unroll
                for (int r = 0; r < 4; r++)
                    Cs[wm * 64 + rt * 16 + g * 4 + r][wn * 64 + ct * 16 + c] = f2bf(acc[rt][ct][r]);
        __syncthreads();
        int dcol = tid >> 1, sh = tid & 1;
        int bb2 = mt >> 4;
        int s0r = (mt & 15) * 128;
        #pragma unroll
        for (int jj = 0; jj < 8; jj++) {
            bf16x8 v;
            #pragma unroll
            for (int e = 0; e < 8; e++) v[e] = (short)Cs[sh * 64 + jj * 8 + e][dcol];
            *(bf16x8*)(VTo + ((size_t)(bb2 * 512 + nt * 128 + dcol)) * 2048 + s0r + sh * 64 + jj * 8) = v;
        }
    }
}

// ---------------------------------------------------------------------------
// Kernel 3 (v10 = v8 verbatim): wave-specialized flash attention + PV V-tile
// prefetch. v9's chain-split + setprio REGRESSED (112 -> 121.4 us, MfmaUtil
// 25.8 -> 23.5): the QK^T chain wasn't the critical path, and prioritizing
// both roles' MFMA clusters cancels out. Reverted.
// ---------------------------------------------------------------------------
#define STAGE_K(tt) do {                                                        \
    _Pragma("unroll")                                                           \
    for (int i_ = 0; i_ < 4; i_++) {                                            \
        int r_ = wid * 4 + i_;                                                  \
        gl_lds16(Kb + (size_t)((tt) * 64 + r_) * 512 + ((lane ^ (r_ & 7)) * 8), \
                 &Ks[(tt) & 1][r_ * 512]);                                      \
    }                                                                           \
} while (0)

__global__ __launch_bounds__(1024, 4) void attn_kernel(const unsigned short* __restrict__ Qg,
        const unsigned short* __restrict__ Kg, const unsigned short* __restrict__ VTg,
        float* __restrict__ out) {
    __shared__ __align__(16) unsigned short Ks[2][64 * 512];  // 128 KB, swizzled
    __shared__ __align__(16) unsigned short Ps[2][64][72];    // 18.4 KB, dbuf
    __shared__ float psum_s[64][2];

    int bid = blockIdx.x;
    int swz = (bid & 7) * 32 + (bid >> 3);  // XCD x owns batch x
    int b = swz >> 5, qt = swz & 31;
    int tid = threadIdx.x;
    int lane = tid & 63, wid = tid >> 6;    // wid 0..15
    int c = lane & 15, g = lane >> 4;

    const unsigned short* Qb = Qg + ((size_t)(b * 2048 + qt * 64)) * 512;
    const unsigned short* Kb = Kg + ((size_t)b * 2048) * 512;
    const unsigned short* Vb = VTg + ((size_t)b * 512) * 2048;

    // ---- stage Q (swizzled source) into Ks[0] — all waves
    #pragma unroll
    for (int i = 0; i < 4; i++) {
        int r = wid * 4 + i;
        gl_lds16(Qb + (size_t)r * 512 + ((lane ^ (r & 7)) * 8), &Ks[0][r * 512]);
    }

    if (wid < 8) {
        // ================= score waves =================
        int sqg = wid >> 1;          // q-row group (0..3), two waves each
        int skg = (wid & 1) * 2;     // first of two 16-col kv groups (0 or 2)
        __syncthreads();             // A: Q DMA done (vmcnt0)
        bf16x8 qf[16];
        {
            int row = sqg * 16 + c;
            #pragma unroll
            for (int ks = 0; ks < 16; ks++)
                qf[ks] = *(const bf16x8*)&Ks[0][row * 512 + (((ks * 4 + g) ^ (row & 7)) * 8)];
        }
        __syncthreads();             // B: Q reads done before K(0) overwrite
        STAGE_K(0);

        float accs[8];
        #pragma unroll
        for (int j = 0; j < 8; j++) accs[j] = 0.0f;

        for (int t = 0; t < 32; t++) {
            __syncthreads();         // K(t) staged; Ps(t) buffer free
            if (t + 1 < 32) STAGE_K(t + 1);

            const unsigned short* KsC = &Ks[t & 1][0];
            const f32x4 fz = {0.f, 0.f, 0.f, 0.f};
            f32x4 s0 = fz, s1 = fz;
            int kr0 = skg * 16 + c;
            int kr1 = kr0 + 16;
            #pragma unroll
            for (int ks = 0; ks < 16; ks++) {
                bf16x8 bk0 = *(const bf16x8*)&KsC[kr0 * 512 + (((ks * 4 + g) ^ (kr0 & 7)) * 8)];
                bf16x8 bk1 = *(const bf16x8*)&KsC[kr1 * 512 + (((ks * 4 + g) ^ (kr1 & 7)) * 8)];
                s0 = __builtin_amdgcn_mfma_f32_16x16x32_bf16(qf[ks], bk0, s0, 0, 0, 0);
                s1 = __builtin_amdgcn_mfma_f32_16x16x32_bf16(qf[ks], bk1, s1, 0, 0, 0);
            }
            unsigned short* PsW = &Ps[t & 1][0][0];
            #pragma unroll
            for (int r = 0; r < 4; r++) {
                int row = sqg * 16 + g * 4 + r;
                float p0 = __expf(s0[r]);
                float p1 = __expf(s1[r]);
                accs[r] += p0;
                accs[4 + r] += p1;
                PsW[row * 72 + skg * 16 + c] = f2bf(p0);
                PsW[row * 72 + (skg + 1) * 16 + c] = f2bf(p1);
            }
        }

        // final row-sum reduction into psum_s
        #pragma unroll
        for (int r = 0; r < 4; r++) {
            float v = accs[r] + accs[4 + r];
            v += __shfl_xor(v, 1);
            v += __shfl_xor(v, 2);
            v += __shfl_xor(v, 4);
            v += __shfl_xor(v, 8);
            if (c == 0) psum_s[sqg * 16 + g * 4 + r][wid & 1] = v;
        }
        __syncthreads();             // C: Ps(31) + psum_s published
    } else {
        // ================= PV waves =================
        int pcol = (wid - 8) * 64;   // d-column base (0..448)
        const unsigned short* Vp = Vb + (size_t)(pcol + c) * 2048 + g * 8;
        __syncthreads();             // A
        __syncthreads();             // B
        STAGE_K(0);

        f32x4 o[16];
        {
            const f32x4 fz = {0.f, 0.f, 0.f, 0.f};
            #pragma unroll
            for (int i = 0; i < 16; i++) o[i] = fz;
        }
        bf16x8 bva[4];               // V(t, h0) prefetched one tile ahead
        #pragma unroll
        for (int ct = 0; ct < 4; ct++)
            bva[ct] = *(const bf16x8*)(Vp + (size_t)(ct * 16) * 2048);

        for (int t = 0; t < 32; t++) {
            __syncthreads();         // K(t) staged; Ps(t-1) visible
            if (t + 1 < 32) STAGE_K(t + 1);
            if (t > 0) {
                int tp = t - 1;
                const unsigned short* PsR = &Ps[tp & 1][0][0];
                bf16x8 bvb[4];       // V(tp, h1): issue now, use after h0 MFMAs
                #pragma unroll
                for (int ct = 0; ct < 4; ct++)
                    bvb[ct] = *(const bf16x8*)(Vp + (size_t)(ct * 16) * 2048 + tp * 64 + 32);
                #pragma unroll
                for (int rt = 0; rt < 4; rt++) {
                    bf16x8 pa = *(const bf16x8*)&PsR[(rt * 16 + c) * 72 + g * 8];
                    #pragma unroll
                    for (int ct = 0; ct < 4; ct++)
                        o[rt * 4 + ct] = __builtin_amdgcn_mfma_f32_16x16x32_bf16(
                            pa, bva[ct], o[rt * 4 + ct], 0, 0, 0);
                }
                #pragma unroll
                for (int ct = 0; ct < 4; ct++)   // prefetch V(t, h0) for next tile
                    bva[ct] = *(const bf16x8*)(Vp + (size_t)(ct * 16) * 2048 + t * 64);
                #pragma unroll
                for (int rt = 0; rt < 4; rt++) {
                    bf16x8 pa = *(const bf16x8*)&PsR[(rt * 16 + c) * 72 + 32 + g * 8];
                    #pragma unroll
                    for (int ct = 0; ct < 4; ct++)
                        o[rt * 4 + ct] = __builtin_amdgcn_mfma_f32_16x16x32_bf16(
                            pa, bvb[ct], o[rt * 4 + ct], 0, 0, 0);
                }
            }
        }
        __syncthreads();             // C: Ps(31) + psum_s visible
        {
            const unsigned short* PsR = &Ps[31 & 1][0][0];
            bf16x8 bvb[4];
            #pragma unroll
            for (int ct = 0; ct < 4; ct++)
                bvb[ct] = *(const bf16x8*)(Vp + (size_t)(ct * 16) * 2048 + 31 * 64 + 32);
            #pragma unroll
            for (int rt = 0; rt < 4; rt++) {
                bf16x8 pa = *(const bf16x8*)&PsR[(rt * 16 + c) * 72 + g * 8];
                #pragma unroll
                for (int ct = 0; ct < 4; ct++)
                    o[rt * 4 + ct] = __builtin_amdgcn_mfma_f32_16x16x32_bf16(
                        pa, bva[ct], o[rt * 4 + ct], 0, 0, 0);
            }
            #pragma unroll
            for (int rt = 0; rt < 4; rt++) {
                bf16x8 pa = *(const bf16x8*)&PsR[(rt * 16 + c) * 72 + 32 + g * 8];
                #pragma unroll
                for (int ct = 0; ct < 4; ct++)
                    o[rt * 4 + ct] = __builtin_amdgcn_mfma_f32_16x16x32_bf16(
                        pa, bvb[ct], o[rt * 4 + ct], 0, 0, 0);
            }
        }

        float* ob = out + ((size_t)(b * 2048 + qt * 64)) * 512;
        #pragma unroll
        for (int rt = 0; rt < 4; rt++)
            #pragma unroll
            for (int r = 0; r < 4; r++) {
                int lrow = rt * 16 + g * 4 + r;
                float l = psum_s[lrow][0] + psum_s[lrow][1];
                float inv = 1.0f / l;
                #pragma unroll
                for (int ct = 0; ct < 4; ct++)
                    ob[(size_t)lrow * 512 + pcol + ct * 16 + c] = o[rt * 4 + ct][r] * inv;
            }
    }
}

// ---------------------------------------------------------------------------
extern "C" void kernel_launch(void* const* d_in, const int* in_sizes, int n_in,
                              void* d_out, int out_size, void* d_ws, size_t ws_size,
                              hipStream_t stream) {
    const float* x = (const float*)d_in[0];   // [8][2048][512] fp32
    const float* W = (const float*)d_in[1];   // [3][512][512] fp32
    float* out = (float*)d_out;               // [8][2048][512] fp32
    char* ws = (char*)d_ws;
    unsigned short* WT = (unsigned short*)(ws);
    unsigned short* Q  = (unsigned short*)(ws + (size_t)2  * 1024 * 1024);
    unsigned short* K  = (unsigned short*)(ws + (size_t)18 * 1024 * 1024);
    unsigned short* VT = (unsigned short*)(ws + (size_t)34 * 1024 * 1024);
    // x-bf16 scratch lives in the OUTPUT buffer (16.7 MB of 33.5 MB); it is
    // fully dead before attn_kernel overwrites every element of out.
    unsigned short* xb = (unsigned short*)d_out;

    pre_kernel<<<4288, 256, 0, stream>>>(W, WT, x, xb);
    proj_kernel<<<1536, 256, 0, stream>>>(xb, WT, Q, K, VT);
    attn_kernel<<<256, 1024, 0, stream>>>(Q, K, VT, out);
}

// Round 9
// 144.470 us; speedup vs baseline: 1.0923x; 1.0323x over previous
//
#include <hip/hip_runtime.h>
#include <hip/hip_bf16.h>

typedef __attribute__((ext_vector_type(8))) short bf16x8;
typedef __attribute__((ext_vector_type(4))) float f32x4;

#define DEV static __device__ __forceinline__

DEV unsigned short f2bf(float f) {
    union { __hip_bfloat16 h; unsigned short u; } cv;
    cv.h = __float2bfloat16(f);
    return cv.u;
}

DEV bf16x8 cvt8(f32x4 lo, f32x4 hi) {
    bf16x8 u;
    u[0] = (short)f2bf(lo[0]); u[1] = (short)f2bf(lo[1]);
    u[2] = (short)f2bf(lo[2]); u[3] = (short)f2bf(lo[3]);
    u[4] = (short)f2bf(hi[0]); u[5] = (short)f2bf(hi[1]);
    u[6] = (short)f2bf(hi[2]); u[7] = (short)f2bf(hi[3]);
    return u;
}

typedef __attribute__((address_space(1))) const void gas_t;
typedef __attribute__((address_space(3))) void las_t;

DEV void gl_lds16(const void* g, void* l) {
    __builtin_amdgcn_global_load_lds((gas_t*)g, (las_t*)l, 16, 0, 0);
}

// ---------------------------------------------------------------------------
// Kernel 1 (v11): W [3][512][512] fp32 -> WT bf16 transposed only (x-pass
// eliminated — proj now stages x fp32 directly). W0 pre-scaled by 1/sqrt(512).
// ---------------------------------------------------------------------------
__global__ __launch_bounds__(256, 2) void wt_kernel(const float* __restrict__ W,
                                                    unsigned short* __restrict__ WT) {
    __shared__ __align__(16) unsigned short T[64][72];
    int bid = blockIdx.x;
    int w = bid >> 6;
    int rem = bid & 63;
    int kt = rem >> 3, nt = rem & 7;
    int t = threadIdx.x;
    int r = t >> 2, cq = t & 3;
    const float* src = W + ((size_t)(w * 512 + kt * 64 + r)) * 512 + nt * 64 + cq * 16;
    float sc = (w == 0) ? 0.04419417382415922f : 1.0f;  // 1/sqrt(512)
    #pragma unroll
    for (int i = 0; i < 4; i++) {
        float4 f = *(const float4*)(src + 4 * i);
        T[r][cq * 16 + 4 * i + 0] = f2bf(f.x * sc);
        T[r][cq * 16 + 4 * i + 1] = f2bf(f.y * sc);
        T[r][cq * 16 + 4 * i + 2] = f2bf(f.z * sc);
        T[r][cq * 16 + 4 * i + 3] = f2bf(f.w * sc);
    }
    __syncthreads();
    int n = t >> 2, kq = t & 3;
    bf16x8 v0, v1;
    #pragma unroll
    for (int e = 0; e < 8; e++) v0[e] = (short)T[kq * 16 + e][n];
    #pragma unroll
    for (int e = 0; e < 8; e++) v1[e] = (short)T[kq * 16 + 8 + e][n];
    unsigned short* dst = WT + ((size_t)(w * 512 + nt * 64 + n)) * 512 + kt * 64 + kq * 16;
    *(bf16x8*)dst = v0;
    *(bf16x8*)(dst + 8) = v1;
}

// ---------------------------------------------------------------------------
// Kernel 2 (v11): QKV projection. A-operand = x staged as FP32 via
// global_load_lds (16 KB/buf, 8 chunks of 16B per row, pos = ch ^ (row&7)),
// converted to bf16 at fragment read (2x ds_read_b128 + 8 cvt). B = WT bf16
// staged as before. As/Bs (48 KB) and Cs (33.8 KB) overlay in one smem block
// (Cs only live after the k-loop) so 2 blocks/CU are preserved.
// ---------------------------------------------------------------------------
#define STAGE_P(kk) do {                                                          \
    _Pragma("unroll")                                                             \
    for (int i_ = 0; i_ < 4; i_++) {   /* A: fp32, 8 rows/wave/iter */            \
        int r_ = wid * 32 + i_ * 8 + (lane >> 3);                                 \
        int ch_ = (lane & 7) ^ (r_ & 7);                                          \
        gl_lds16(xp + (size_t)r_ * 512 + (kk) * 32 + ch_ * 4,                     \
                 &As[((kk) & 1) * 4096 + (wid * 32 + i_ * 8) * 32]);              \
    }                                                                             \
    _Pragma("unroll")                                                             \
    for (int j_ = 0; j_ < 2; j_++) {   /* B: bf16, 16 rows/wave/iter */           \
        int r_ = wid * 32 + j_ * 16 + (lane >> 2);                                \
        int ch_ = (lane & 3) ^ (r_ & 3);                                          \
        gl_lds16(wp + (size_t)r_ * 512 + (kk) * 32 + ch_ * 8,                     \
                 &Bs[((kk) & 1) * 4096 + (wid * 32 + j_ * 16) * 32]);             \
    }                                                                             \
} while (0)

__global__ __launch_bounds__(256, 2) void proj_kernel(const float* __restrict__ x,
        const unsigned short* __restrict__ WT,
        unsigned short* __restrict__ Qo, unsigned short* __restrict__ Ko,
        unsigned short* __restrict__ VTo) {
    __shared__ __align__(16) char smem[49152];
    float* As = (float*)smem;                              // [2][128*32] fp32
    unsigned short* Bs = (unsigned short*)(smem + 32768);  // [2][128*32] bf16
    unsigned short* Cs = (unsigned short*)smem;            // [128][132] (post-loop)

    int bid = blockIdx.x;
    int swz = (bid & 7) * 192 + (bid >> 3);
    int mt = swz / 12;
    int rem = swz - mt * 12;
    int w = rem >> 2, nt = rem & 3;
    int tid = threadIdx.x;
    int lane = tid & 63, wid = tid >> 6;
    int wm = wid >> 1, wn = wid & 1;
    int c = lane & 15, g = lane >> 4;

    const float* xp = x + (size_t)(mt * 128) * 512;
    const unsigned short* wp = WT + ((size_t)(w * 512 + nt * 128)) * 512;

    const f32x4 fz = {0.f, 0.f, 0.f, 0.f};
    f32x4 acc[4][4];
    #pragma unroll
    for (int i = 0; i < 4; i++)
        #pragma unroll
        for (int j = 0; j < 4; j++) acc[i][j] = fz;

    STAGE_P(0);
    for (int kk = 0; kk < 16; kk++) {
        __syncthreads();                 // buf[kk&1] DMA drained (vmcnt0)
        if (kk + 1 < 16) STAGE_P(kk + 1);
        const float* Ac = &As[(kk & 1) * 4096];
        const unsigned short* Bc = &Bs[(kk & 1) * 4096];
        bf16x8 a[4], bb[4];
        #pragma unroll
        for (int rt = 0; rt < 4; rt++) {
            int row = wm * 64 + rt * 16 + c;
            f32x4 lo = *(const f32x4*)&Ac[row * 32 + (((2 * g) ^ (row & 7)) * 4)];
            f32x4 hi = *(const f32x4*)&Ac[row * 32 + (((2 * g + 1) ^ (row & 7)) * 4)];
            a[rt] = cvt8(lo, hi);
        }
        #pragma unroll
        for (int ct = 0; ct < 4; ct++) {
            int row = wn * 64 + ct * 16 + c;
            bb[ct] = *(const bf16x8*)&Bc[row * 32 + ((g ^ (row & 3)) * 8)];
        }
        __builtin_amdgcn_s_setprio(1);
        #pragma unroll
        for (int rt = 0; rt < 4; rt++)
            #pragma unroll
            for (int ct = 0; ct < 4; ct++)
                acc[rt][ct] = __builtin_amdgcn_mfma_f32_16x16x32_bf16(a[rt], bb[ct], acc[rt][ct], 0, 0, 0);
        __builtin_amdgcn_s_setprio(0);
    }

    if (w < 2) {
        unsigned short* dst = (w == 0) ? Qo : Ko;
        #pragma unroll
        for (int rt = 0; rt < 4; rt++)
            #pragma unroll
            for (int ct = 0; ct < 4; ct++)
                #pragma unroll
                for (int r = 0; r < 4; r++) {
                    int grow = mt * 128 + wm * 64 + rt * 16 + g * 4 + r;
                    int gcol = nt * 128 + wn * 64 + ct * 16 + c;
                    dst[(size_t)grow * 512 + gcol] = f2bf(acc[rt][ct][r]);
                }
    } else {
        __syncthreads();                 // all As/Bs reads retired before Cs overlay
        #pragma unroll
        for (int rt = 0; rt < 4; rt++)
            #pragma unroll
            for (int ct = 0; ct < 4; ct++)
                #pragma unroll
                for (int r = 0; r < 4; r++)
                    Cs[(wm * 64 + rt * 16 + g * 4 + r) * 132 + (wn * 64 + ct * 16 + c)] = f2bf(acc[rt][ct][r]);
        __syncthreads();
        int dcol = tid >> 1, sh = tid & 1;
        int bb2 = mt >> 4;
        int s0r = (mt & 15) * 128;
        #pragma unroll
        for (int jj = 0; jj < 8; jj++) {
            bf16x8 v;
            #pragma unroll
            for (int e = 0; e < 8; e++) v[e] = (short)Cs[(sh * 64 + jj * 8 + e) * 132 + dcol];
            *(bf16x8*)(VTo + ((size_t)(bb2 * 512 + nt * 128 + dcol)) * 2048 + s0r + sh * 64 + jj * 8) = v;
        }
    }
}

// ---------------------------------------------------------------------------
// Kernel 3 (v10/v8, UNCHANGED): wave-specialized flash attention + PV V-tile
// prefetch. 113 us, MfmaUtil 25.8 — banked best; do not touch this round.
// ---------------------------------------------------------------------------
#define STAGE_K(tt) do {                                                        \
    _Pragma("unroll")                                                           \
    for (int i_ = 0; i_ < 4; i_++) {                                            \
        int r_ = wid * 4 + i_;                                                  \
        gl_lds16(Kb + (size_t)((tt) * 64 + r_) * 512 + ((lane ^ (r_ & 7)) * 8), \
                 &Ks[(tt) & 1][r_ * 512]);                                      \
    }                                                                           \
} while (0)

__global__ __launch_bounds__(1024, 4) void attn_kernel(const unsigned short* __restrict__ Qg,
        const unsigned short* __restrict__ Kg, const unsigned short* __restrict__ VTg,
        float* __restrict__ out) {
    __shared__ __align__(16) unsigned short Ks[2][64 * 512];  // 128 KB, swizzled
    __shared__ __align__(16) unsigned short Ps[2][64][72];    // 18.4 KB, dbuf
    __shared__ float psum_s[64][2];

    int bid = blockIdx.x;
    int swz = (bid & 7) * 32 + (bid >> 3);  // XCD x owns batch x
    int b = swz >> 5, qt = swz & 31;
    int tid = threadIdx.x;
    int lane = tid & 63, wid = tid >> 6;    // wid 0..15
    int c = lane & 15, g = lane >> 4;

    const unsigned short* Qb = Qg + ((size_t)(b * 2048 + qt * 64)) * 512;
    const unsigned short* Kb = Kg + ((size_t)b * 2048) * 512;
    const unsigned short* Vb = VTg + ((size_t)b * 512) * 2048;

    // ---- stage Q (swizzled source) into Ks[0] — all waves
    #pragma unroll
    for (int i = 0; i < 4; i++) {
        int r = wid * 4 + i;
        gl_lds16(Qb + (size_t)r * 512 + ((lane ^ (r & 7)) * 8), &Ks[0][r * 512]);
    }

    if (wid < 8) {
        // ================= score waves =================
        int sqg = wid >> 1;          // q-row group (0..3), two waves each
        int skg = (wid & 1) * 2;     // first of two 16-col kv groups (0 or 2)
        __syncthreads();             // A: Q DMA done (vmcnt0)
        bf16x8 qf[16];
        {
            int row = sqg * 16 + c;
            #pragma unroll
            for (int ks = 0; ks < 16; ks++)
                qf[ks] = *(const bf16x8*)&Ks[0][row * 512 + (((ks * 4 + g) ^ (row & 7)) * 8)];
        }
        __syncthreads();             // B: Q reads done before K(0) overwrite
        STAGE_K(0);

        float accs[8];
        #pragma unroll
        for (int j = 0; j < 8; j++) accs[j] = 0.0f;

        for (int t = 0; t < 32; t++) {
            __syncthreads();         // K(t) staged; Ps(t) buffer free
            if (t + 1 < 32) STAGE_K(t + 1);

            const unsigned short* KsC = &Ks[t & 1][0];
            const f32x4 fz = {0.f, 0.f, 0.f, 0.f};
            f32x4 s0 = fz, s1 = fz;
            int kr0 = skg * 16 + c;
            int kr1 = kr0 + 16;
            #pragma unroll
            for (int ks = 0; ks < 16; ks++) {
                bf16x8 bk0 = *(const bf16x8*)&KsC[kr0 * 512 + (((ks * 4 + g) ^ (kr0 & 7)) * 8)];
                bf16x8 bk1 = *(const bf16x8*)&KsC[kr1 * 512 + (((ks * 4 + g) ^ (kr1 & 7)) * 8)];
                s0 = __builtin_amdgcn_mfma_f32_16x16x32_bf16(qf[ks], bk0, s0, 0, 0, 0);
                s1 = __builtin_amdgcn_mfma_f32_16x16x32_bf16(qf[ks], bk1, s1, 0, 0, 0);
            }
            unsigned short* PsW = &Ps[t & 1][0][0];
            #pragma unroll
            for (int r = 0; r < 4; r++) {
                int row = sqg * 16 + g * 4 + r;
                float p0 = __expf(s0[r]);
                float p1 = __expf(s1[r]);
                accs[r] += p0;
                accs[4 + r] += p1;
                PsW[row * 72 + skg * 16 + c] = f2bf(p0);
                PsW[row * 72 + (skg + 1) * 16 + c] = f2bf(p1);
            }
        }

        // final row-sum reduction into psum_s
        #pragma unroll
        for (int r = 0; r < 4; r++) {
            float v = accs[r] + accs[4 + r];
            v += __shfl_xor(v, 1);
            v += __shfl_xor(v, 2);
            v += __shfl_xor(v, 4);
            v += __shfl_xor(v, 8);
            if (c == 0) psum_s[sqg * 16 + g * 4 + r][wid & 1] = v;
        }
        __syncthreads();             // C: Ps(31) + psum_s published
    } else {
        // ================= PV waves =================
        int pcol = (wid - 8) * 64;   // d-column base (0..448)
        const unsigned short* Vp = Vb + (size_t)(pcol + c) * 2048 + g * 8;
        __syncthreads();             // A
        __syncthreads();             // B
        STAGE_K(0);

        f32x4 o[16];
        {
            const f32x4 fz = {0.f, 0.f, 0.f, 0.f};
            #pragma unroll
            for (int i = 0; i < 16; i++) o[i] = fz;
        }
        bf16x8 bva[4];               // V(t, h0) prefetched one tile ahead
        #pragma unroll
        for (int ct = 0; ct < 4; ct++)
            bva[ct] = *(const bf16x8*)(Vp + (size_t)(ct * 16) * 2048);

        for (int t = 0; t < 32; t++) {
            __syncthreads();         // K(t) staged; Ps(t-1) visible
            if (t + 1 < 32) STAGE_K(t + 1);
            if (t > 0) {
                int tp = t - 1;
                const unsigned short* PsR = &Ps[tp & 1][0][0];
                bf16x8 bvb[4];       // V(tp, h1): issue now, use after h0 MFMAs
                #pragma unroll
                for (int ct = 0; ct < 4; ct++)
                    bvb[ct] = *(const bf16x8*)(Vp + (size_t)(ct * 16) * 2048 + tp * 64 + 32);
                #pragma unroll
                for (int rt = 0; rt < 4; rt++) {
                    bf16x8 pa = *(const bf16x8*)&PsR[(rt * 16 + c) * 72 + g * 8];
                    #pragma unroll
                    for (int ct = 0; ct < 4; ct++)
                        o[rt * 4 + ct] = __builtin_amdgcn_mfma_f32_16x16x32_bf16(
                            pa, bva[ct], o[rt * 4 + ct], 0, 0, 0);
                }
                #pragma unroll
                for (int ct = 0; ct < 4; ct++)   // prefetch V(t, h0) for next tile
                    bva[ct] = *(const bf16x8*)(Vp + (size_t)(ct * 16) * 2048 + t * 64);
                #pragma unroll
                for (int rt = 0; rt < 4; rt++) {
                    bf16x8 pa = *(const bf16x8*)&PsR[(rt * 16 + c) * 72 + 32 + g * 8];
                    #pragma unroll
                    for (int ct = 0; ct < 4; ct++)
                        o[rt * 4 + ct] = __builtin_amdgcn_mfma_f32_16x16x32_bf16(
                            pa, bvb[ct], o[rt * 4 + ct], 0, 0, 0);
                }
            }
        }
        __syncthreads();             // C: Ps(31) + psum_s visible
        {
            const unsigned short* PsR = &Ps[31 & 1][0][0];
            bf16x8 bvb[4];
            #pragma unroll
            for (int ct = 0; ct < 4; ct++)
                bvb[ct] = *(const bf16x8*)(Vp + (size_t)(ct * 16) * 2048 + 31 * 64 + 32);
            #pragma unroll
            for (int rt = 0; rt < 4; rt++) {
                bf16x8 pa = *(const bf16x8*)&PsR[(rt * 16 + c) * 72 + g * 8];
                #pragma unroll
                for (int ct = 0; ct < 4; ct++)
                    o[rt * 4 + ct] = __builtin_amdgcn_mfma_f32_16x16x32_bf16(
                        pa, bva[ct], o[rt * 4 + ct], 0, 0, 0);
            }
            #pragma unroll
            for (int rt = 0; rt < 4; rt++) {
                bf16x8 pa = *(const bf16x8*)&PsR[(rt * 16 + c) * 72 + 32 + g * 8];
                #pragma unroll
                for (int ct = 0; ct < 4; ct++)
                    o[rt * 4 + ct] = __builtin_amdgcn_mfma_f32_16x16x32_bf16(
                        pa, bvb[ct], o[rt * 4 + ct], 0, 0, 0);
            }
        }

        float* ob = out + ((size_t)(b * 2048 + qt * 64)) * 512;
        #pragma unroll
        for (int rt = 0; rt < 4; rt++)
            #pragma unroll
            for (int r = 0; r < 4; r++) {
                int lrow = rt * 16 + g * 4 + r;
                float l = psum_s[lrow][0] + psum_s[lrow][1];
                float inv = 1.0f / l;
                #pragma unroll
                for (int ct = 0; ct < 4; ct++)
                    ob[(size_t)lrow * 512 + pcol + ct * 16 + c] = o[rt * 4 + ct][r] * inv;
            }
    }
}

// ---------------------------------------------------------------------------
extern "C" void kernel_launch(void* const* d_in, const int* in_sizes, int n_in,
                              void* d_out, int out_size, void* d_ws, size_t ws_size,
                              hipStream_t stream) {
    const float* x = (const float*)d_in[0];   // [8][2048][512] fp32
    const float* W = (const float*)d_in[1];   // [3][512][512] fp32
    float* out = (float*)d_out;               // [8][2048][512] fp32
    char* ws = (char*)d_ws;
    unsigned short* WT = (unsigned short*)(ws);
    unsigned short* Q  = (unsigned short*)(ws + (size_t)2  * 1024 * 1024);
    unsigned short* K  = (unsigned short*)(ws + (size_t)18 * 1024 * 1024);
    unsigned short* VT = (unsigned short*)(ws + (size_t)34 * 1024 * 1024);

    wt_kernel<<<192, 256, 0, stream>>>(W, WT);
    proj_kernel<<<1536, 256, 0, stream>>>(x, WT, Q, K, VT);
    attn_kernel<<<256, 1024, 0, stream>>>(Q, K, VT, out);
}